// Round 13
// baseline (258.328 us; speedup 1.0000x reference)
//
#include <hip/hip_runtime.h>
#include <math.h>

#define N_NODES 500000
#define G_SEG   25000
#define H_DIM   256
#define SPB     4      // segments per kF block (one per wave)

typedef __attribute__((ext_vector_type(4))) float f32x4;
typedef __attribute__((ext_vector_type(8))) short bf16x8;

__device__ __forceinline__ float leaky(float x){ return x > 0.f ? x : 0.01f * x; }

// round-to-nearest-even f32 -> bf16
__device__ __forceinline__ ushort f2bf(float f){
  unsigned u = __float_as_uint(f);
  u += 0x7FFFu + ((u >> 16) & 1u);
  return (ushort)(u >> 16);
}

// KPrep v2: block = 4 waves; wave w owns segment g = b*4+w for the k1 duty.
// Side duties: blocks 0..1953: starts[]; 2000..2255: Bp; 2256..2767: Bp6.
__global__ __launch_bounds__(256) void kPrep(
    const float* __restrict__ sn, const float* __restrict__ w_align,
    const int* __restrict__ seg, const float* __restrict__ w_att,
    const float* __restrict__ w_ih, const float* __restrict__ w_hh,
    float* __restrict__ s_buf, float* __restrict__ sws,
    int* __restrict__ starts, ushort* __restrict__ Bp,
    ushort* __restrict__ Bp6)
{
  int b = blockIdx.x, t = threadIdx.x;
  int wv = t >> 6, lane = t & 63;

  {
    int g = b * 4 + wv;
    f32x4 sv = ((const f32x4*)(sn + (size_t)g * H_DIM))[lane];
    f32x4 wa = ((const f32x4*)(w_align + H_DIM))[lane];
    #pragma unroll
    for (int e = 0; e < 4; e++) sv[e] = leaky(sv[e]);
    ((f32x4*)(s_buf + (size_t)g * H_DIM))[lane] = sv;
    float p = sv[0]*wa[0] + sv[1]*wa[1] + sv[2]*wa[2] + sv[3]*wa[3];
    #pragma unroll
    for (int d = 1; d < 64; d <<= 1) p += __shfl_xor(p, d);
    if (lane == 0) sws[g] = p;
  }

  if (b < 1954) {
    int i = b * 256 + t;
    if (i < N_NODES) {
      int s = seg[i];
      int prev = (i == 0) ? -1 : seg[i - 1];
      for (int g = prev + 1; g <= s; g++) starts[g] = i;
      if (i == N_NODES - 1)
        for (int g = s + 1; g <= G_SEG; g++) starts[g] = N_NODES;
    }
  }
  else if (b >= 2000 && b < 2256) {
    int kk = b - 2000;
    Bp[(((kk >> 3) << 8) + t) * 8 + (kk & 7)] = f2bf(w_att[kk * H_DIM + t]);
  }
  else if (b >= 2256 && b < 2768) {
    int kk = b - 2256;  // 0..511
    #pragma unroll
    for (int gate = 0; gate < 4; gate++) {
      float v;
      if (gate == 0)      v = (kk < 256) ? w_ih[kk * 768 + t]        : w_hh[(kk - 256) * 768 + t];
      else if (gate == 1) v = (kk < 256) ? w_ih[kk * 768 + 256 + t]  : w_hh[(kk - 256) * 768 + 256 + t];
      else if (gate == 2) v = (kk < 256) ? w_ih[kk * 768 + 512 + t]  : 0.f;
      else                v = (kk < 256) ? 0.f                       : w_hh[(kk - 256) * 768 + 512 + t];
      int n = (gate << 8) + t;
      Bp6[(((kk >> 3) << 10) + n) * 8 + (kk & 7)] = f2bf(v);
    }
  }
}

// KF v6: wave-per-segment, 8-row transpose-reduce batches.
// Per 8 rows: 6 shfl reduce + 1 leaky/exp per lane + 3 shfl max + 8 shfl
// broadcast (vs 14 shfl + 2 exp per 8 rows in v5). 8 loads in flight at
// iteration start. Tail: classic per-row butterfly.
__global__ __launch_bounds__(256) void kF_score_softmax_agg(
    const float* __restrict__ node, const int* __restrict__ starts,
    const float* __restrict__ w_align, const float* __restrict__ b_align,
    const float* __restrict__ sws,
    float* __restrict__ attn_out, float* __restrict__ agg,
    float* __restrict__ bscale)
{
  __shared__ int st_s[SPB + 1];
  const int tid = threadIdx.x;
  const int g0 = blockIdx.x * SPB;
  if (tid <= SPB) st_s[tid] = starts[g0 + tid];
  __syncthreads();

  const int wv = tid >> 6, lane = tid & 63;
  const float4 wvec = ((const float4*)w_align)[lane];
  const float b0 = b_align[0];

  const int g  = g0 + wv;
  const int st = st_s[wv], en = st_s[wv + 1];
  const float swsg = sws[g];

  float m = -3.4e38f, sum = 0.f;
  f32x4 pacc = {0.f, 0.f, 0.f, 0.f};

  int r = st;
  for (; r + 7 < en; r += 8) {
    f32x4 a0 = ((const f32x4*)node)[(size_t)(r    ) * 64 + lane];
    f32x4 a1 = ((const f32x4*)node)[(size_t)(r + 1) * 64 + lane];
    f32x4 a2 = ((const f32x4*)node)[(size_t)(r + 2) * 64 + lane];
    f32x4 a3 = ((const f32x4*)node)[(size_t)(r + 3) * 64 + lane];
    f32x4 a4 = ((const f32x4*)node)[(size_t)(r + 4) * 64 + lane];
    f32x4 a5 = ((const f32x4*)node)[(size_t)(r + 5) * 64 + lane];
    f32x4 a6 = ((const f32x4*)node)[(size_t)(r + 6) * 64 + lane];
    f32x4 a7 = ((const f32x4*)node)[(size_t)(r + 7) * 64 + lane];
    float d0 = a0[0]*wvec.x + a0[1]*wvec.y + a0[2]*wvec.z + a0[3]*wvec.w;
    float d1 = a1[0]*wvec.x + a1[1]*wvec.y + a1[2]*wvec.z + a1[3]*wvec.w;
    float d2 = a2[0]*wvec.x + a2[1]*wvec.y + a2[2]*wvec.z + a2[3]*wvec.w;
    float d3 = a3[0]*wvec.x + a3[1]*wvec.y + a3[2]*wvec.z + a3[3]*wvec.w;
    float d4 = a4[0]*wvec.x + a4[1]*wvec.y + a4[2]*wvec.z + a4[3]*wvec.w;
    float d5 = a5[0]*wvec.x + a5[1]*wvec.y + a5[2]*wvec.z + a5[3]*wvec.w;
    float d6 = a6[0]*wvec.x + a6[1]*wvec.y + a6[2]*wvec.z + a6[3]*wvec.w;
    float d7 = a7[0]*wvec.x + a7[1]*wvec.y + a7[2]*wvec.z + a7[3]*wvec.w;

    // transpose-reduce level 1 (xor 1): row base + (lane&1)
    float k01 = (lane & 1) ? d1 : d0, s01 = (lane & 1) ? d0 : d1;
    k01 += __shfl_xor(s01, 1);
    float k23 = (lane & 1) ? d3 : d2, s23 = (lane & 1) ? d2 : d3;
    k23 += __shfl_xor(s23, 1);
    float k45 = (lane & 1) ? d5 : d4, s45 = (lane & 1) ? d4 : d5;
    k45 += __shfl_xor(s45, 1);
    float k67 = (lane & 1) ? d7 : d6, s67 = (lane & 1) ? d6 : d7;
    k67 += __shfl_xor(s67, 1);
    // level 2 (xor 2): row (lane&3) within each quad
    float xa = (lane & 2) ? k23 : k01, sa = (lane & 2) ? k01 : k23;
    xa += __shfl_xor(sa, 2);
    float xb = (lane & 2) ? k67 : k45, sb = (lane & 2) ? k45 : k67;
    xb += __shfl_xor(sb, 2);
    // level 3 (xor 4): row (lane&7)
    float x = (lane & 4) ? xb : xa, sx = (lane & 4) ? xa : xb;
    x += __shfl_xor(sx, 4);
    // butterfly over 8 replicated groups
    x += __shfl_xor(x, 8);
    x += __shfl_xor(x, 16);
    x += __shfl_xor(x, 32);
    // x = dot for row r + (lane&7)

    float sc = leaky(x + swsg + b0);
    if (lane < 8) attn_out[r + lane] = sc;   // park raw score

    float bm = fmaxf(sc, __shfl_xor(sc, 1));
    bm = fmaxf(bm, __shfl_xor(bm, 2));
    bm = fmaxf(bm, __shfl_xor(bm, 4));       // wave-uniform batch max
    if (bm > m) {
      float scale = __expf(m - bm);          // first time: exp(-inf) = 0
      sum *= scale; pacc *= scale; m = bm;
    }
    float p = __expf(sc - m);                // this lane's row only
    float p0 = __shfl(p, 0), p1 = __shfl(p, 1);
    float p2 = __shfl(p, 2), p3 = __shfl(p, 3);
    float p4 = __shfl(p, 4), p5 = __shfl(p, 5);
    float p6 = __shfl(p, 6), p7 = __shfl(p, 7);
    sum += ((p0 + p1) + (p2 + p3)) + ((p4 + p5) + (p6 + p7));
    pacc += p0 * a0 + p1 * a1;
    pacc += p2 * a2 + p3 * a3;
    pacc += p4 * a4 + p5 * a5;
    pacc += p6 * a6 + p7 * a7;
  }
  // tail rows: classic full butterfly
  for (; r < en; r++) {
    f32x4 a = ((const f32x4*)node)[(size_t)r * 64 + lane];
    float d = a[0]*wvec.x + a[1]*wvec.y + a[2]*wvec.z + a[3]*wvec.w;
    #pragma unroll
    for (int s2 = 1; s2 < 64; s2 <<= 1) d += __shfl_xor(d, s2);
    float sc = leaky(d + swsg + b0);
    if (lane == 0) attn_out[r] = sc;
    if (sc <= m) {
      float p = __expf(sc - m);
      sum += p;
      pacc += p * a;
    } else {
      float scale = __expf(m - sc);
      sum = sum * scale + 1.f;
      pacc = pacc * scale + a;
      m = sc;
    }
  }

  // wave-local finalize
  float invD = (sum > 0.f) ? 1.f / sum : 0.f;
  ((f32x4*)(agg + (size_t)g * H_DIM))[lane] = pacc * invD;
  if (lane == 0) bscale[g] = (sum > 0.f) ? 1.f : 0.f;
  for (int rr = st + lane; rr < en; rr += 64)
    attn_out[rr] = __expf(attn_out[rr] - m) * invD;
}

// K5b v2 (MFMA): ctx_bf16 = bf16(elu(agg @ w_attend + bscale*b_attend)).
// Stores elu'd bf16 (12.8 MB) — k6 stages it without cvt/elu.
__global__ __launch_bounds__(256, 2) void k5b_ctx(
    const float* __restrict__ agg, const ushort* __restrict__ Bp,
    const float* __restrict__ b_att, const float* __restrict__ bscale,
    ushort* __restrict__ ctx_bf16)
{
  __shared__ __align__(16) ushort A_lds[128 * 256];  // 64KB

  const int tid  = threadIdx.x;
  const int row0 = blockIdx.x * 128;

  #pragma unroll
  for (int i = 0; i < 16; i++) {
    int v = tid + i * 256;
    int r = v >> 5;
    int s = v & 31;
    int grow = row0 + r;
    f32x4 x0 = {0.f, 0.f, 0.f, 0.f}, x1 = {0.f, 0.f, 0.f, 0.f};
    if (grow < G_SEG) {
      const f32x4* p = (const f32x4*)(agg + (size_t)grow * H_DIM) + s * 2;
      x0 = p[0]; x1 = p[1];
    }
    bf16x8 t;
    t[0] = (short)f2bf(x0[0]); t[1] = (short)f2bf(x0[1]);
    t[2] = (short)f2bf(x0[2]); t[3] = (short)f2bf(x0[3]);
    t[4] = (short)f2bf(x1[0]); t[5] = (short)f2bf(x1[1]);
    t[6] = (short)f2bf(x1[2]); t[7] = (short)f2bf(x1[3]);
    *(bf16x8*)&A_lds[r * 256 + ((s ^ (r & 7)) * 8)] = t;
  }
  __syncthreads();

  const int wv  = tid >> 6;
  const int l   = tid & 63;
  const int l15 = l & 15, lq = l >> 4, l7 = l & 7;
  const int colbase = wv * 64 + l15;

  f32x4 acc[8][4];
  #pragma unroll
  for (int mf = 0; mf < 8; mf++)
    #pragma unroll
    for (int nf = 0; nf < 4; nf++)
      acc[mf][nf] = (f32x4){0.f, 0.f, 0.f, 0.f};

  for (int ks = 0; ks < 8; ks++) {
    int c = ks * 4 + lq;
    bf16x8 b[4];
    #pragma unroll
    for (int nf = 0; nf < 4; nf++)
      b[nf] = *(const bf16x8*)&Bp[(((c << 8) + colbase + nf * 16)) * 8];
    bf16x8 a[8];
    #pragma unroll
    for (int mf = 0; mf < 8; mf++)
      a[mf] = *(const bf16x8*)&A_lds[(mf * 16 + l15) * 256 + ((c ^ l7) * 8)];
    #pragma unroll
    for (int mf = 0; mf < 8; mf++)
      #pragma unroll
      for (int nf = 0; nf < 4; nf++)
        acc[mf][nf] = __builtin_amdgcn_mfma_f32_16x16x32_bf16(
            a[mf], b[nf], acc[mf][nf], 0, 0, 0);
  }

  float bias[4];
  #pragma unroll
  for (int nf = 0; nf < 4; nf++) bias[nf] = b_att[colbase + nf * 16];

  #pragma unroll
  for (int mf = 0; mf < 8; mf++) {
    #pragma unroll
    for (int r = 0; r < 4; r++) {
      int grow = row0 + mf * 16 + lq * 4 + r;
      if (grow < G_SEG) {
        float bsc = bscale[grow];
        #pragma unroll
        for (int nf = 0; nf < 4; nf++) {
          float val = acc[mf][nf][r] + bias[nf] * bsc;
          val = val > 0.f ? val : (__expf(val) - 1.f);  // elu here
          ctx_bf16[(size_t)grow * H_DIM + colbase + nf * 16] = f2bf(val);
        }
      }
    }
  }
}

// K6 v4: ctx arrives as elu'd bf16 — staging is a straight 16B copy for
// slots 0..31; s_buf converts as before. 64 rows/block, 8 waves.
__global__ __launch_bounds__(512, 2) void k6_mfma(
    const ushort* __restrict__ ctx_bf16, const float* __restrict__ s_buf,
    const ushort* __restrict__ Bp6,
    const float* __restrict__ b_ih, const float* __restrict__ b_hh,
    float* __restrict__ out0)
{
  __shared__ __align__(16) ushort A_lds[64 * 512];   // 64KB

  const int tid  = threadIdx.x;
  const int row0 = blockIdx.x * 64;

  #pragma unroll
  for (int i = 0; i < 8; i++) {
    int v = tid + i * 512;
    int r = v >> 6;          // 0..63
    int s = v & 63;
    int g = row0 + r;
    bf16x8 t = {0,0,0,0,0,0,0,0};
    if (g < G_SEG) {
      if (s < 32) {
        t = ((const bf16x8*)(ctx_bf16 + (size_t)g * H_DIM))[s];
      } else {
        const f32x4* p = (const f32x4*)(s_buf + (size_t)g * H_DIM) + (s - 32) * 2;
        f32x4 y0 = p[0], y1 = p[1];
        t[0] = (short)f2bf(y0[0]); t[1] = (short)f2bf(y0[1]);
        t[2] = (short)f2bf(y0[2]); t[3] = (short)f2bf(y0[3]);
        t[4] = (short)f2bf(y1[0]); t[5] = (short)f2bf(y1[1]);
        t[6] = (short)f2bf(y1[2]); t[7] = (short)f2bf(y1[3]);
      }
    }
    *(bf16x8*)&A_lds[r * 512 + ((s ^ (r & 7)) * 8)] = t;
  }
  __syncthreads();

  const int wv  = tid >> 6;          // 0..7
  const int rh  = (wv >> 2) * 32;    // row half base
  const int cw  = (wv & 3) << 6;     // col slice base
  const int l   = tid & 63;
  const int l15 = l & 15, lq = l >> 4, l7 = l & 7;

  f32x4 acc[4][2][4];  // [gate][mf][nf]
  #pragma unroll
  for (int gt = 0; gt < 4; gt++)
    #pragma unroll
    for (int mf = 0; mf < 2; mf++)
      #pragma unroll
      for (int nf = 0; nf < 4; nf++)
        acc[gt][mf][nf] = (f32x4){0.f, 0.f, 0.f, 0.f};

  for (int ks = 0; ks < 16; ks++) {
    int c = ks * 4 + lq;  // k-chunk 0..63
    bf16x8 a[2];
    #pragma unroll
    for (int mf = 0; mf < 2; mf++)
      a[mf] = *(const bf16x8*)&A_lds[(rh + mf * 16 + l15) * 512 + ((c ^ l7) * 8)];
    #pragma unroll
    for (int gt = 0; gt < 4; gt++) {
      if (gt == 2 && ks >= 8) continue;  // inn: K<256 only
      if (gt == 3 && ks < 8) continue;   // hn:  K>=256 only
      #pragma unroll
      for (int nf = 0; nf < 4; nf++) {
        int n = (gt << 8) + cw + nf * 16 + l15;
        bf16x8 b = *(const bf16x8*)&Bp6[(((c << 10) + n)) * 8];
        acc[gt][0][nf] = __builtin_amdgcn_mfma_f32_16x16x32_bf16(
            a[0], b, acc[gt][0][nf], 0, 0, 0);
        acc[gt][1][nf] = __builtin_amdgcn_mfma_f32_16x16x32_bf16(
            a[1], b, acc[gt][1][nf], 0, 0, 0);
      }
    }
  }

  #pragma unroll
  for (int nf = 0; nf < 4; nf++) {
    int cc = cw + nf * 16 + l15;
    float bir = b_ih[cc] + b_hh[cc];
    float biz = b_ih[256 + cc] + b_hh[256 + cc];
    float bin_ = b_ih[512 + cc];
    float bhn  = b_hh[512 + cc];
    #pragma unroll
    for (int mf = 0; mf < 2; mf++) {
      #pragma unroll
      for (int rr = 0; rr < 4; rr++) {
        int grow = row0 + rh + mf * 16 + lq * 4 + rr;
        if (grow < G_SEG) {
          float v0 = acc[0][mf][nf][rr];
          float v1 = acc[1][mf][nf][rr];
          float v2 = acc[2][mf][nf][rr];
          float v3 = acc[3][mf][nf][rr];
          float r_ = 1.f / (1.f + __expf(-(v0 + bir)));
          float z_ = 1.f / (1.f + __expf(-(v1 + biz)));
          float n_ = tanhf(v2 + bin_ + r_ * (v3 + bhn));
          float sv = s_buf[(size_t)grow * H_DIM + cc];
          float nh = (1.f - z_) * n_ + z_ * sv;
          out0[(size_t)grow * H_DIM + cc] = nh > 0.f ? nh : 0.f;
        }
      }
    }
  }
}

extern "C" void kernel_launch(void* const* d_in, const int* in_sizes, int n_in,
                              void* d_out, int out_size, void* d_ws, size_t ws_size,
                              hipStream_t stream)
{
  (void)in_sizes; (void)n_in; (void)out_size; (void)ws_size;
  const float* node       = (const float*)d_in[0];
  const float* super_node = (const float*)d_in[1];
  const int*   seg        = (const int*)d_in[2];
  const float* w_align    = (const float*)d_in[3];
  const float* b_align    = (const float*)d_in[4];
  const float* w_att      = (const float*)d_in[5];
  const float* b_att      = (const float*)d_in[6];
  const float* w_ih       = (const float*)d_in[7];
  const float* w_hh       = (const float*)d_in[8];
  const float* b_ih       = (const float*)d_in[9];
  const float* b_hh       = (const float*)d_in[10];

  float* out0     = (float*)d_out;                               // G*H
  float* attn_out = (float*)d_out + (size_t)G_SEG * H_DIM;       // N

  float* ws     = (float*)d_ws;
  float* s_buf  = ws;                          //  6,400,000 f32
  float* sws    = ws + 6400000;                //     25,000
  float* agg    = ws + 6425000;                //  6,400,000
  ushort* Bp    = (ushort*)(ws + 12825000);    //  65,536 ushort (128KB)
  ushort* Bp6   = (ushort*)(ws + 12860000);    // 524,288 ushort (1MB)
  float* bscale = ws + 13125000;               //     25,000
  int*   starts = (int*)(ws + 13150000);       //     25,001 int
  ushort* ctx_bf16 = (ushort*)(ws + 13200000); //  6,400,000 ushort (12.8MB)

  kPrep<<<G_SEG / 4, 256, 0, stream>>>(super_node, w_align, seg, w_att, w_ih, w_hh,
                                       s_buf, sws, starts, Bp, Bp6);
  kF_score_softmax_agg<<<G_SEG / SPB, 256, 0, stream>>>(
      node, starts, w_align, b_align, sws, attn_out, agg, bscale);
  k5b_ctx<<<(G_SEG + 127) / 128, 256, 0, stream>>>(agg, Bp, b_att, bscale, ctx_bf16);
  k6_mfma<<<(G_SEG + 63) / 64, 512, 0, stream>>>(ctx_bf16, s_buf, Bp6, b_ih, b_hh, out0);
}